// Round 1
// 215.287 us; speedup vs baseline: 1.1278x; 1.1278x over previous
//
#include <hip/hip_runtime.h>
#include <math.h>

#define NBb 16
#define NTt 50
#define NAa 5
#define NHh 128
#define NWw 128
#define NCc 20
#define NCH 26                       // 6 + NC channels
#define NCELL (NBb*NAa*NHh*NWw)      // 1,310,720 cells
#define NREC  (NBb*NTt)              // 800 records
#define NLIST (NREC*7)               // max touched-cell list entries
#define SCALE_F 16.0f
#define IGNORE_THRES_F 0.5f
#define BAD_CONF_WEIGHT_F 1.25f
#define PI_F 3.14159265358979323846f

// ws layout (32-bit units):
//  [0..10] accumulators: 0=acc_all 1=sub 2=cnb 3=obj 4=sx 5=sy 6=sw 7=sh 8=sr 9=scls 10=cm
//  [15] list counter (uint)
//  [16 .. 16+NCELL)   status grid (uint32): 0=bg, 1=ignored, 2+rec=masked
//  rec: tx,ty,tw,th,tr (float[NREC] each) + tlab (int[NREC])
//  list: touched cell ids (uint[NLIST], may contain duplicates)
#define STATUS_OFF 16
#define REC_OFF  (STATUS_OFF + NCELL)
#define LIST_OFF (REC_OFF + 6*NREC)

#define MAIN_GRID 1024
#define MAIN_BLK  256
#define MAIN_STRIDE (MAIN_GRID*MAIN_BLK)   // 262,144; NCELL == 5*MAIN_STRIDE exactly
static_assert(NCELL == 5 * MAIN_STRIDE, "conf loop unroll assumes 5 cells/thread");
static_assert(((STATUS_OFF + NCELL) & 3) == 0, "k_zero uint4 alignment");

__device__ __forceinline__ float inv_tanh_f(float y) {
  if (y <= -1.0f) return -2.0f;
  if (y >= 1.0f)  return  2.0f;
  float ys = fminf(fmaxf(y, -1.0f + 1e-6f), 1.0f - 1e-6f);
  return 0.5f * logf((1.0f + ys) / (1.0f - ys));
}

// softplus(z) = max(z,0) + log1p(exp(-|z|))  == BCE(z, target=0)
__device__ __forceinline__ float softplus_f(float z) {
  return fmaxf(z, 0.0f) + log1pf(expf(-fabsf(z)));
}

// Zero accumulators + list counter + status grid (ws is 0xAA-poisoned each call).
__global__ void k_zero(uint4* __restrict__ ws4) {
  const int n4 = (STATUS_OFF + NCELL) / 4;   // 327,684
  int stride = gridDim.x * blockDim.x;
  for (int i = blockIdx.x * blockDim.x + threadIdx.x; i < n4; i += stride)
    ws4[i] = make_uint4(0u, 0u, 0u, 0u);
}

__global__ void k_prep(const float* __restrict__ tgt,
                       const int* __restrict__ tsz,
                       const float* __restrict__ anch,
                       float* __restrict__ ws) {
  int tid = blockIdx.x * blockDim.x + threadIdx.x;
  if (tid >= NREC) return;
  int b = tid / NTt, t = tid % NTt;

  float aw[NAa], ah[NAa], ar[NAa], ahw[NAa], ap[NAa][8];
  for (int a = 0; a < NAa; ++a) {
    aw[a] = anch[a*3+0] / SCALE_F;
    ah[a] = anch[a*3+1] / SCALE_F;
    ar[a] = anch[a*3+2];
    float cr = cosf(ar[a]), sr = sinf(ar[a]);
    ap[a][0] = -cr*aw[a]; ap[a][1] =  sr*aw[a];
    ap[a][2] =  cr*aw[a]; ap[a][3] = -sr*aw[a];
    ap[a][4] = -sr*ah[a]; ap[a][5] = -cr*ah[a];
    ap[a][6] =  sr*ah[a]; ap[a][7] =  cr*ah[a];
    ahw[a] = (ah[a] + aw[a]) * 0.5f;
  }

  const float* row = tgt + (size_t)tid * (13 + NCc);
  float gx = row[0] / SCALE_F;
  float gy = row[1] / SCALE_F;
  float gr = row[2];
  float gh = row[3] / SCALE_F;
  float gw = row[4] / SCALE_F;
  bool valid = (t < tsz[b]) && (gw != 0.0f) && (gh != 0.0f);
  if (!valid) return;

  int gi = (int)gx; gi = min(max(gi, 0), NWw - 1);
  int gj = (int)gy; gj = min(max(gj, 0), NHh - 1);

  float cp[8];
  for (int k = 0; k < 8; ++k)
    cp[k] = row[5 + k] / SCALE_F - ((k & 1) ? gy : gx);

  float bestd = 1e30f; int best = 0; unsigned ignm = 0;
  for (int a = 0; a < NAa; ++a) {
    float dn = 0.0f;
    for (int p = 0; p < 8; p += 2) {
      float dx = cp[p]   - ap[a][p];
      float dy = cp[p+1] - ap[a][p+1];
      dn += sqrtf(dx*dx + dy*dy);
    }
    float nm = ((gh + gw) * 0.5f + ahw[a]) * 0.5f;
    float d = dn / nm; d = d * d;
    if (d < IGNORE_THRES_F) ignm |= (1u << a);
    if (d < bestd) { bestd = d; best = a; }
  }

  unsigned* wsu = (unsigned*)ws;
  unsigned* status = wsu + STATUS_OFF;
  unsigned* list = wsu + LIST_OFF;
  int cellbase = ((b * NAa) * NHh + gj) * NWw + gi;
  for (int a = 0; a < NAa; ++a)
    if ((ignm >> a) & 1u) {
      int cell = cellbase + a * NHh * NWw;
      atomicMax(&status[cell], 1u);
      unsigned slot = atomicAdd(&wsu[15], 1u);
      list[slot] = (unsigned)cell;
    }
  {
    int cell = cellbase + best * NHh * NWw;
    // mask scatter: 2+rec; atomicMax => mask beats ignore, last target wins
    atomicMax(&status[cell], 2u + (unsigned)tid);
    if (!((ignm >> best) & 1u)) {           // avoid duplicate list entry
      unsigned slot = atomicAdd(&wsu[15], 1u);
      list[slot] = (unsigned)cell;
    }
  }

  float txv = inv_tanh_f(gx - ((float)gi + 0.5f));
  float tyv = inv_tanh_f(gy - ((float)gj + 0.5f));
  float rd = gr - ar[best];
  if (rd > PI_F) rd -= 2.0f * PI_F;
  else if (rd < -PI_F) rd += 2.0f * PI_F;
  float trv = inv_tanh_f(rd / (PI_F * 0.5f));
  float twv = logf(gw / aw[best] + 1e-16f);
  float thv = logf(gh / ah[best] + 1e-16f);
  int tlab = 0; float bm = row[13];
  for (int c = 1; c < NCc; ++c)
    if (row[13 + c] > bm) { bm = row[13 + c]; tlab = c; }

  float* rec = ws + REC_OFF;
  rec[0*NREC + tid] = txv;
  rec[1*NREC + tid] = tyv;
  rec[2*NREC + tid] = twv;
  rec[3*NREC + tid] = thv;
  rec[4*NREC + tid] = trv;
  ((int*)rec)[5*NREC + tid] = tlab;
}

// Fused streaming + correction kernel.
// Phase 1: each thread reads ONLY the conf channel (stride-26 dword gather)
//          of exactly 5 cells — no mod-13, no divergent branch, ~1/10 the
//          VALU work of the old float4 full-tensor stream.
// Phase 2: grid-stride over the touched-cell list (<=4800 entries); claim
//          each cell once via atomicExch, accumulate corrections + masked
//          losses. Runs grid-wide (old version was a single block).
__global__ void __launch_bounds__(MAIN_BLK) k_main(const float* __restrict__ pred,
                                                   float* __restrict__ ws) {
  unsigned* wsu = (unsigned*)ws;
  unsigned* status = wsu + STATUS_OFF;
  const unsigned* list = wsu + LIST_OFF;
  const float* rec = ws + REC_OFF;
  int nlist = (int)wsu[15];
  int t = blockIdx.x * MAIN_BLK + threadIdx.x;

  // ---- Phase 1: softplus(conf) over all cells, 5 cells/thread, unrolled ----
  float acc = 0.0f;
  #pragma unroll
  for (int k = 0; k < 5; ++k) {
    float z = pred[(size_t)(t + k * MAIN_STRIDE) * NCH];
    acc += softplus_f(z);
  }

  // ---- Phase 2: corrections for ignored/masked cells ----
  float sub = 0.0f, cnb = 0.0f, obj = 0.0f;
  float sx = 0.0f, sy = 0.0f, sw = 0.0f, sh = 0.0f, sr = 0.0f;
  float scls = 0.0f, cm = 0.0f;

  for (int i = t; i < nlist; i += MAIN_STRIDE) {
    unsigned cell = list[i];
    unsigned st = atomicExch(&status[cell], 0u);   // claim; dedups duplicates
    if (st == 0u) continue;
    const float* cp = pred + (size_t)cell * NCH;
    float z = cp[0];
    sub += softplus_f(z);
    cnb += 1.0f;
    if (st >= 2u) {
      int r = (int)(st - 2u);
      obj += softplus_f(z) - z;               // BCE(z, target=1)
      float dx = cp[1] - rec[0*NREC + r];
      float dy = cp[2] - rec[1*NREC + r];
      float dr = cp[3] - rec[4*NREC + r];
      float dh = cp[4] - rec[3*NREC + r];
      float dw = cp[5] - rec[2*NREC + r];
      sx += dx*dx; sy += dy*dy; sw += dw*dw; sh += dh*dh; sr += dr*dr;
      int tlab = ((const int*)rec)[5*NREC + r];
      float m = cp[6];
      for (int c = 1; c < NCc; ++c) m = fmaxf(m, cp[6 + c]);
      float s = 0.0f;
      for (int c = 0; c < NCc; ++c) s += expf(cp[6 + c] - m);
      scls += (m + logf(s)) - cp[6 + tlab];
      cm += 1.0f;
    }
  }

  // ---- block reduction: 11 partials, shfl within wave then LDS across 4 waves ----
  float vals[11] = {acc, sub, cnb, obj, sx, sy, sw, sh, sr, scls, cm};
  __shared__ float red[4][11];
  int wid = threadIdx.x >> 6, lane = threadIdx.x & 63;
  #pragma unroll
  for (int k = 0; k < 11; ++k) {
    float v = vals[k];
    for (int off = 32; off; off >>= 1) v += __shfl_down(v, off, 64);
    if (lane == 0) red[wid][k] = v;
  }
  __syncthreads();
  if (threadIdx.x < 11) {
    float v = red[0][threadIdx.x] + red[1][threadIdx.x]
            + red[2][threadIdx.x] + red[3][threadIdx.x];
    if (v != 0.0f) atomicAdd(ws + threadIdx.x, v);  // most blocks: 1 atomic (acc)
  }
}

// Combine the 11 accumulators into the scalar loss.
__global__ void k_fin(const float* __restrict__ ws, float* __restrict__ out) {
  if (threadIdx.x == 0) {
    float acc = ws[0], sub = ws[1], cnb = ws[2], obj = ws[3];
    float sx = ws[4], sy = ws[5], sw = ws[6], sh = ws[7], sr = ws[8];
    float scls = ws[9], cm = ws[10];
    float acc_bg = acc - sub;
    float cnt_bg = (float)NCELL - cnb;
    float db = fmaxf(cnt_bg, 1.0f);
    float dm = fmaxf(cm, 1.0f);
    float loss_conf = BAD_CONF_WEIGHT_F * (acc_bg / db) + obj / dm;
    out[0] = (sx + sy + sw + sh + sr + scls) / dm + loss_conf;
  }
}

extern "C" void kernel_launch(void* const* d_in, const int* in_sizes, int n_in,
                              void* d_out, int out_size, void* d_ws, size_t ws_size,
                              hipStream_t stream) {
  const float* pred = (const float*)d_in[0];   // (16,5,128,128,26)
  const float* tgt  = (const float*)d_in[1];   // (16,50,33)
  const int*   tsz  = (const int*)d_in[2];     // (16,)
  const float* anch = (const float*)d_in[3];   // (5,3)
  float* ws = (float*)d_ws;

  k_zero<<<320, 256, 0, stream>>>((uint4*)ws);
  k_prep<<<4, 256, 0, stream>>>(tgt, tsz, anch, ws);
  k_main<<<MAIN_GRID, MAIN_BLK, 0, stream>>>(pred, ws);
  k_fin<<<1, 64, 0, stream>>>(ws, (float*)d_out);
}